// Round 1
// baseline (123.389 us; speedup 1.0000x reference)
//
#include <hip/hip_runtime.h>

// ---------------------------------------------------------------------------
// Problem constants: B=4, S=4096 -> N=16384 rows. DIM=256, DF=128, DS=128,
// GF=5, GS=5, K=3, P=0.5. Fourier GEMM: K1 = 2*DF*GF = 1280 -> 128 cols.
// Spline GEMM: K2 = DS (tanh/base) + DS*(GS+K)=1024 (bspline) = 1152 -> 128.
// Output f32 (N,256) -> LayerNorm over 256 -> *ln_w+ln_b -> *scale_w.
// ---------------------------------------------------------------------------

typedef __attribute__((ext_vector_type(8))) _Float16 half8;
typedef __attribute__((ext_vector_type(4))) float f32x4;

#define NROWS   16384
#define KT1     40      // 1280/32 k-tiles
#define KT2     36      // 1152/32 k-tiles
#define NFRAG1  20480   // 8 ntiles * 40 ktiles * 64 lanes
#define NFRAG2  18432   // 8 ntiles * 36 ktiles * 64 lanes
#define FSTRIDE 136     // LDS feature tile row stride (elems), 272B: 2-way max

// spline grid: g[m] = (m-3)*0.4 - 1.0 computed in double then cast (matches np)
__device__ constexpr float grd(int m) { return (float)((double)(m - 3) * 0.4 - 1.0); }

// ---------------------------------------------------------------------------
// Prep: repack weights to f16 in MFMA B-fragment order.
// B-frag for 16x16x32: lane l holds B[k0 + (l>>4)*8 + e][n0 + (l&15)], e=0..7.
// Wf k-order: k = part*640 + g*128 + d  (part: 0=cos,1=sin)
// Ws k-order: k<128 -> base_weight[o][k]; else spline_weight[o][(k-128)/8][(k-128)%8]
// ---------------------------------------------------------------------------
__global__ __launch_bounds__(256) void prep_kernel(
    const float* __restrict__ FWSRC,   // (2,128,128,5)
    const float* __restrict__ BW,      // (128,128)
    const float* __restrict__ SW,      // (128,128,8)
    _Float16* __restrict__ WFP, _Float16* __restrict__ WSP)
{
    int tt = blockIdx.x * 256 + threadIdx.x;
    if (tt < NFRAG1) {
        int nt  = tt / (KT1 * 64);
        int rem = tt - nt * (KT1 * 64);
        int kt = rem >> 6, l = rem & 63;
        int o  = nt * 16 + (l & 15);
        int kb = kt * 32 + (l >> 4) * 8;
        half8 v;
#pragma unroll
        for (int e = 0; e < 8; ++e) {
            int k = kb + e;
            int part = (k >= 640);
            int kk = k - part * 640;
            int d = kk & 127, g = kk >> 7;
            v[e] = (_Float16)FWSRC[part * 81920 + o * 640 + d * 5 + g];
        }
        *reinterpret_cast<half8*>(WFP + ((size_t)tt << 3)) = v;
    } else if (tt < NFRAG1 + NFRAG2) {
        int t2 = tt - NFRAG1;
        int nt  = t2 / (KT2 * 64);
        int rem = t2 - nt * (KT2 * 64);
        int kt = rem >> 6, l = rem & 63;
        int o  = nt * 16 + (l & 15);
        int kb = kt * 32 + (l >> 4) * 8;
        half8 v;
#pragma unroll
        for (int e = 0; e < 8; ++e) {
            int k = kb + e;
            v[e] = (_Float16)((k < 128) ? BW[o * 128 + k] : SW[o * 1024 + (k - 128)]);
        }
        *reinterpret_cast<half8*>(WSP + ((size_t)t2 << 3)) = v;
    }
}

// ---------------------------------------------------------------------------
// Fused main kernel: 256 blocks x 512 threads. Block = 64 rows.
// 8 waves; wave w owns output cols [16w,16w+16) of each GEMM half.
// Per K-chunk of 128: compute features -> LDS -> 4 ktiles x 4 rowtiles MFMA.
// ---------------------------------------------------------------------------
__global__ __launch_bounds__(512) void fused_kernel(
    const float* __restrict__ TS,      // (16384)
    const float* __restrict__ FTHETA,  // (128)
    const float* __restrict__ BFOUR,   // (128)
    const float* __restrict__ W1W,     // (128)
    const float* __restrict__ W1B,     // (128)
    const float* __restrict__ LNW,     // (256)
    const float* __restrict__ LNB,     // (256)
    const float* __restrict__ SCW,     // (256)
    const _Float16* __restrict__ WFP,  // packed fourier weights
    const _Float16* __restrict__ WSP,  // packed spline weights
    float* __restrict__ OUT)           // (16384,256)
{
    __shared__ __align__(16) _Float16 feat[64 * FSTRIDE];
    __shared__ float tsS[64];
    __shared__ float fwS[128], bfS[128], w1wS[128], w1bS[128];
    __shared__ float redS[64][9], redQ[64][9];
    __shared__ float muS[64], rsS[64];

    const int tid  = threadIdx.x;
    const int lane = tid & 63;
    const int w    = tid >> 6;
    const int la15 = lane & 15;
    const int lhi  = lane >> 4;
    const int row0 = blockIdx.x * 64;

    if (tid < 64) tsS[tid] = TS[row0 + tid];
    if (tid >= 64 && tid < 192) {
        int d = tid - 64;
        float th = FTHETA[d];
        float sp = (th > 20.f) ? th : log1pf(__expf(th));       // softplus
        float ex = (float)((double)d * (9.0 / 127.0));          // linspace(0,9,128)
        float bfq = 1.0f / powf(10.0f, ex);                     // base_freq
        fwS[d] = bfq * (sp + 1e-6f);                            // freq_weight
        bfS[d] = BFOUR[d];
    }
    if (tid >= 192 && tid < 320) {
        int d = tid - 192;
        w1wS[d] = W1W[d];
        w1bS[d] = W1B[d];
    }
    __syncthreads();

    f32x4 acc1[4] = {};
    f32x4 acc2[4] = {};

    // ---------------- GEMM1: fourier features (K = 1280, 10 chunks) ---------
    for (int ch = 0; ch < 10; ++ch) {
        const bool sinp = (ch >= 5);
        const int g = sinp ? ch - 5 : ch;
        const float kf = (float)(g + 1);
#pragma unroll
        for (int q = 0; q < 2; ++q) {
            int task = q * 512 + tid;          // 1024 tasks: (row, grp-of-8)
            int row = task >> 4, grp = task & 15;
            float t = tsS[row];
            half8 v;
#pragma unroll
            for (int e = 0; e < 8; ++e) {
                int d = grp * 8 + e;
                float arg = (t * fwS[d] + bfS[d]) * kf;
                float val = sinp ? __sinf(arg) : __cosf(arg);
                v[e] = (_Float16)val;
            }
            *reinterpret_cast<half8*>(&feat[row * FSTRIDE + grp * 8]) = v;
        }
        __syncthreads();
#pragma unroll
        for (int kt = 0; kt < 4; ++kt) {
            const half8 b = *reinterpret_cast<const half8*>(
                WFP + ((size_t)((w * KT1 + ch * 4 + kt) * 64 + lane) << 3));
#pragma unroll
            for (int rt = 0; rt < 4; ++rt) {
                const half8 a = *reinterpret_cast<const half8*>(
                    &feat[(rt * 16 + la15) * FSTRIDE + kt * 32 + lhi * 8]);
                acc1[rt] = __builtin_amdgcn_mfma_f32_16x16x32_f16(a, b, acc1[rt], 0, 0, 0);
            }
        }
        __syncthreads();
    }

    // ---------------- GEMM2: tanh + bspline features (K = 1152, 9 chunks) ---
    for (int ch = 0; ch < 9; ++ch) {
#pragma unroll
        for (int q = 0; q < 2; ++q) {
            int task = q * 512 + tid;
            int row = task >> 4, grp = task & 15;
            float t = tsS[row];
            half8 v;
            if (ch == 0) {
#pragma unroll
                for (int e = 0; e < 8; ++e) {
                    int d = grp * 8 + e;
                    float x = t * w1wS[d] + w1bS[d];
                    v[e] = (_Float16)tanhf(x);
                }
            } else {
                int d = 16 * (ch - 1) + grp;
                float x = t * w1wS[d] + w1bS[d];
                float bb[11];
#pragma unroll
                for (int m = 0; m < 11; ++m)
                    bb[m] = (x >= grd(m) && x < grd(m + 1)) ? 1.0f : 0.0f;
#pragma unroll
                for (int k = 1; k <= 3; ++k) {
                    const float rk = (float)(1.0 / (0.4 * (double)k));
#pragma unroll
                    for (int m = 0; m + k < 11; ++m)
                        bb[m] = (x - grd(m)) * rk * bb[m] + (grd(m + k + 1) - x) * rk * bb[m + 1];
                }
                half8 vv;
#pragma unroll
                for (int e = 0; e < 8; ++e) vv[e] = (_Float16)bb[e];
                v = vv;
            }
            *reinterpret_cast<half8*>(&feat[row * FSTRIDE + grp * 8]) = v;
        }
        __syncthreads();
#pragma unroll
        for (int kt = 0; kt < 4; ++kt) {
            const half8 b = *reinterpret_cast<const half8*>(
                WSP + ((size_t)((w * KT2 + ch * 4 + kt) * 64 + lane) << 3));
#pragma unroll
            for (int rt = 0; rt < 4; ++rt) {
                const half8 a = *reinterpret_cast<const half8*>(
                    &feat[(rt * 16 + la15) * FSTRIDE + kt * 32 + lhi * 8]);
                acc2[rt] = __builtin_amdgcn_mfma_f32_16x16x32_f16(a, b, acc2[rt], 0, 0, 0);
            }
        }
        __syncthreads();
    }

    // ---------------- Epilogue: LayerNorm over 256 cols ----------------------
    // C/D layout (verified, guide §3): col = lane&15, row = (lane>>4)*4 + reg.
#pragma unroll
    for (int rt = 0; rt < 4; ++rt) {
#pragma unroll
        for (int j = 0; j < 4; ++j) {
            float x1 = 0.5f * acc1[rt][j];
            float x2 = 0.5f * acc2[rt][j];
            float s = x1 + x2;
            float qq = x1 * x1 + x2 * x2;
#pragma unroll
            for (int m = 1; m < 16; m <<= 1) {
                s  += __shfl_xor(s, m, 64);
                qq += __shfl_xor(qq, m, 64);
            }
            if (la15 == 0) {
                int r = rt * 16 + lhi * 4 + j;
                redS[r][w] = s;
                redQ[r][w] = qq;
            }
        }
    }
    __syncthreads();
    if (tid < 64) {
        float s = 0.f, qq = 0.f;
#pragma unroll
        for (int wv = 0; wv < 8; ++wv) { s += redS[tid][wv]; qq += redQ[tid][wv]; }
        float mu = s * (1.0f / 256.0f);
        float var = qq * (1.0f / 256.0f) - mu * mu;
        muS[tid] = mu;
        rsS[tid] = rsqrtf(var + 1e-5f);
    }
    __syncthreads();
    {
        int col1 = w * 16 + la15;
        int col2 = col1 + 128;
        float a1 = LNW[col1] * SCW[col1], b1 = LNB[col1] * SCW[col1];
        float a2 = LNW[col2] * SCW[col2], b2 = LNB[col2] * SCW[col2];
#pragma unroll
        for (int rt = 0; rt < 4; ++rt) {
#pragma unroll
            for (int j = 0; j < 4; ++j) {
                int r = rt * 16 + lhi * 4 + j;
                float mu = muS[r], rr = rsS[r];
                float x1 = 0.5f * acc1[rt][j];
                float x2 = 0.5f * acc2[rt][j];
                int base = (row0 + r) * 256;
                OUT[base + col1] = (x1 - mu) * rr * a1 + b1;
                OUT[base + col2] = (x2 - mu) * rr * a2 + b2;
            }
        }
    }
}

extern "C" void kernel_launch(void* const* d_in, const int* in_sizes, int n_in,
                              void* d_out, int out_size, void* d_ws, size_t ws_size,
                              hipStream_t stream) {
    const float* TS     = (const float*)d_in[0];
    const float* FTHETA = (const float*)d_in[1];
    const float* BFOUR  = (const float*)d_in[2];
    const float* FW     = (const float*)d_in[3];
    const float* W1W    = (const float*)d_in[4];
    const float* W1B    = (const float*)d_in[5];
    const float* BW     = (const float*)d_in[6];
    const float* SW     = (const float*)d_in[7];
    const float* SCW    = (const float*)d_in[8];
    const float* LNW    = (const float*)d_in[9];
    const float* LNB    = (const float*)d_in[10];
    float* OUT = (float*)d_out;

    _Float16* WFP = (_Float16*)d_ws;                 // 163840 f16 = 320 KB
    _Float16* WSP = WFP + 163840;                    // 147456 f16 = 288 KB

    hipLaunchKernelGGL(prep_kernel, dim3(152), dim3(256), 0, stream,
                       FW, BW, SW, WFP, WSP);
    hipLaunchKernelGGL(fused_kernel, dim3(256), dim3(512), 0, stream,
                       TS, FTHETA, BFOUR, W1W, W1B, LNW, LNB, SCW, WFP, WSP, OUT);
}

// Round 3
// 111.748 us; speedup vs baseline: 1.1042x; 1.1042x over previous
//
#include <hip/hip_runtime.h>

// B=4,S=4096 -> N=16384 rows. DF=DS=128, GF=GS=5, K=3, P=0.5.
// GEMM1 (fourier): K1=1280, k = d*10 + p*5 + g  (p:0=cos,1=sin; g=0..4 -> harmonic g+1)
// GEMM2 (spline):  K2=1152, k = d*9 + j        (j=0: tanh; j=1..8: basis m=j-1)
// Fused: 256 blocks x 512 thr, 64 rows/block, waves = 2(row)x4(col) grid.
// Double-buffered LDS feature tile, 1 barrier/chunk. LN epilogue in-register.

typedef __attribute__((ext_vector_type(8))) _Float16 half8;
typedef __attribute__((ext_vector_type(2))) __fp16 fp16x2;
typedef __attribute__((ext_vector_type(4))) float f32x4;

#define KN5 -0.19999998807907104f
#define KN6  0.20000004768371582f
#define KN7  0.60000002384185791f

__device__ __forceinline__ unsigned pk(float a, float b) {
    fp16x2 h = __builtin_amdgcn_cvt_pkrtz(a, b);   // lo=a, hi=b
    return __builtin_bit_cast(unsigned, h);
}

// 9 spline-branch values for one x: o0=tanh(x); o1..o8 = cubic B-spline bases 0..7.
// Valid for x in [g5,g8) ~ [-0.2,1.0); actual data x in [0,1).
#define SPL9(x, o0,o1,o2,o3,o4,o5,o6,o7,o8) do {                          \
    float ax_ = fabsf(x);                                                  \
    float e_  = __expf(-2.f*ax_);                                          \
    float th_ = (1.f - e_) * __builtin_amdgcn_rcpf(1.f + e_);              \
    o0 = ((x) < 0.f) ? -th_ : th_;                                         \
    bool b1_ = ((x) >= KN6), b2_ = ((x) >= KN7);                           \
    float kn_ = b2_ ? KN7 : (b1_ ? KN6 : KN5);                             \
    float u_  = ((x) - kn_) * 2.5f;                                        \
    float um_ = 1.f - u_;                                                  \
    float u2_ = u_*u_, u3_ = u2_*u_, um2_ = um_*um_, um3_ = um2_*um_;      \
    float w0_ = (1.f/6.f)*um3_, w3_ = (1.f/6.f)*u3_;                       \
    float w1_ = 0.6666666666666667f - u2_  + 0.5f*u3_;                     \
    float w2_ = 0.6666666666666667f - um2_ + 0.5f*um3_;                    \
    o1 = 0.f; o2 = 0.f;                                                    \
    o3 = b1_ ? 0.f : w0_;                                                  \
    o4 = b2_ ? 0.f : (b1_ ? w0_ : w1_);                                    \
    o5 = b2_ ? w0_ : (b1_ ? w1_ : w2_);                                    \
    o6 = b2_ ? w1_ : (b1_ ? w2_ : w3_);                                    \
    o7 = b2_ ? w2_ : (b1_ ? w3_ : 0.f);                                    \
    o8 = b2_ ? w3_ : 0.f;                                                  \
} while (0)

// ---------------------------------------------------------------------------
// Prep: source-major (coalesced loads), scattered 2B stores.
// B-frag: lane = ((k>>3)&3)*16 + (col&15), e = k&7, frag = (col>>4)*NKT + (k>>5)
// ---------------------------------------------------------------------------
__global__ __launch_bounds__(256) void prep_kernel(
    const float* __restrict__ FW,   // (2,128,128,5)
    const float* __restrict__ BW,   // (128,128)
    const float* __restrict__ SW,   // (128,128,8)
    _Float16* __restrict__ WFP, _Float16* __restrict__ WSP)
{
    int tt = blockIdx.x * 256 + threadIdx.x;
    if (tt < 163840) {
        float val = FW[tt];
        int g = tt % 5;
        int r1 = tt / 5;            // p*16384 + col*128 + d
        int d = r1 & 127;
        int r2 = r1 >> 7;           // p*128 + col
        int col = r2 & 127;
        int p = r2 >> 7;
        int k = d*10 + p*5 + g;
        int idx = (((col>>4)*40 + (k>>5))*64 + ((k>>3)&3)*16 + (col&15))*8 + (k&7);
        WFP[idx] = (_Float16)val;
    } else if (tt < 180224) {
        int s = tt - 163840;
        float val = BW[s];
        int col = s >> 7, d = s & 127;
        int k = d*9;
        int idx = (((col>>4)*36 + (k>>5))*64 + ((k>>3)&3)*16 + (col&15))*8 + (k&7);
        WSP[idx] = (_Float16)val;
    } else if (tt < 311296) {
        int s = tt - 180224;
        float val = SW[s];
        int m = s & 7, d = (s>>3) & 127, col = s >> 10;
        int k = d*9 + m + 1;
        int idx = (((col>>4)*36 + (k>>5))*64 + ((k>>3)&3)*16 + (col&15))*8 + (k&7);
        WSP[idx] = (_Float16)val;
    }
}

// ---------------------------------------------------------------------------
__global__ __launch_bounds__(512) void fused_kernel(
    const float* __restrict__ TS, const float* __restrict__ FTHETA,
    const float* __restrict__ BFOUR, const float* __restrict__ W1W,
    const float* __restrict__ W1B, const float* __restrict__ LNW,
    const float* __restrict__ LNB, const float* __restrict__ SCW,
    const _Float16* __restrict__ WFP, const _Float16* __restrict__ WSP,
    float* __restrict__ OUT)
{
    __shared__ __align__(128) _Float16 feat0[64 * 288];
    __shared__ __align__(128) _Float16 feat1[64 * 288];
    __shared__ float tsS[64], fwS[128], bfS[128], w1wS[128], w1bS[128];
    __shared__ float redS[64][4], redQ[64][4], muS[64], rsS[64];

    const int tid  = threadIdx.x;
    const int lane = tid & 63;
    const int w    = tid >> 6;
    const int wr   = w >> 2, wc = w & 3;
    const int la15 = lane & 15, lhi = lane >> 4;
    const int row0 = blockIdx.x * 64;

    if (tid < 64) tsS[tid] = TS[row0 + tid];
    else if (tid < 192) {
        int d = tid - 64;
        float th = FTHETA[d];
        float sp = (th > 20.f) ? th : log1pf(__expf(th));
        float ex = (float)((double)d * (9.0 / 127.0));
        fwS[d] = (1.0f / powf(10.f, ex)) * (sp + 1e-6f);
        bfS[d] = BFOUR[d];
    } else if (tid < 320) {
        int d = tid - 192;
        w1wS[d] = W1W[d];
        w1bS[d] = W1B[d];
    }
    __syncthreads();

    f32x4 acc1[2][2] = {};
    f32x4 acc2[2][2] = {};

    auto computeFour = [&](int ch, _Float16* buf) {
#pragma unroll
        for (int q = 0; q < 2; ++q) {
            int task = q * 512 + tid;          // 1024 tasks: 64 rows x 16 d
            int row = task >> 4, dd = task & 15;
            int d = (ch << 4) + dd;
            float base = tsS[row] * fwS[d] + bfS[d];
            float s1, c1;
            __sincosf(base, &s1, &c1);
            float tc = c1 + c1;
            float c2 = tc*c1 - 1.f, c3 = tc*c2 - c1, c4 = tc*c3 - c2, c5 = tc*c4 - c3;
            float s2 = tc*s1,       s3 = tc*s2 - s1, s4 = tc*s3 - s2, s5 = tc*s4 - s3;
            char* p = (char*)buf;
            int b = row * 576 + dd * 20;
            int sw = (row & 7) << 4;
            *(unsigned*)(p + ((b +  0) ^ sw)) = pk(c1, c2);
            *(unsigned*)(p + ((b +  4) ^ sw)) = pk(c3, c4);
            *(unsigned*)(p + ((b +  8) ^ sw)) = pk(c5, s1);
            *(unsigned*)(p + ((b + 12) ^ sw)) = pk(s2, s3);
            *(unsigned*)(p + ((b + 16) ^ sw)) = pk(s4, s5);
        }
    };

    auto computeSpl = [&](int ch, _Float16* buf) {
#pragma unroll
        for (int q = 0; q < 2; ++q) {
            int task = q * 512 + tid;          // 1024 tasks: 64 rows x 16 d-pairs
            int row = task >> 4, dp = task & 15;
            float t = tsS[row];
            int d0 = (ch << 5) + dp * 2;
            float x0 = t * w1wS[d0]     + w1bS[d0];
            float x1 = t * w1wS[d0 + 1] + w1bS[d0 + 1];
            float a0,a1,a2,a3,a4,a5,a6,a7,a8;
            float b0,b1,b2,b3,b4,b5,b6,b7,b8;
            SPL9(x0, a0,a1,a2,a3,a4,a5,a6,a7,a8);
            SPL9(x1, b0,b1,b2,b3,b4,b5,b6,b7,b8);
            char* p = (char*)buf;
            int b = row * 576 + dp * 36;
            int sw = (row & 7) << 4;
            *(unsigned*)(p + ((b +  0) ^ sw)) = pk(a0, a1);
            *(unsigned*)(p + ((b +  4) ^ sw)) = pk(a2, a3);
            *(unsigned*)(p + ((b +  8) ^ sw)) = pk(a4, a5);
            *(unsigned*)(p + ((b + 12) ^ sw)) = pk(a6, a7);
            *(unsigned*)(p + ((b + 16) ^ sw)) = pk(a8, b0);
            *(unsigned*)(p + ((b + 20) ^ sw)) = pk(b1, b2);
            *(unsigned*)(p + ((b + 24) ^ sw)) = pk(b3, b4);
            *(unsigned*)(p + ((b + 28) ^ sw)) = pk(b5, b6);
            *(unsigned*)(p + ((b + 32) ^ sw)) = pk(b7, b8);
        }
    };

    auto mfmaFour = [&](int ch, const _Float16* buf) {
        const char* p = (const char*)buf;
#pragma unroll
        for (int kt = 0; kt < 5; ++kt) {
            int ktg = ch * 5 + kt;
            half8 bf0 = *(const half8*)(WFP + (size_t)(((wc*2 + 0)*40 + ktg)*64 + lane) * 8);
            half8 bf1 = *(const half8*)(WFP + (size_t)(((wc*2 + 1)*40 + ktg)*64 + lane) * 8);
#pragma unroll
            for (int rt = 0; rt < 2; ++rt) {
                int row = wr*32 + rt*16 + la15;
                half8 a = *(const half8*)(p + ((row*576 + kt*64 + lhi*16) ^ ((row & 7) << 4)));
                acc1[rt][0] = __builtin_amdgcn_mfma_f32_16x16x32_f16(a, bf0, acc1[rt][0], 0, 0, 0);
                acc1[rt][1] = __builtin_amdgcn_mfma_f32_16x16x32_f16(a, bf1, acc1[rt][1], 0, 0, 0);
            }
        }
    };

    auto mfmaSpl = [&](int ch, const _Float16* buf) {
        const char* p = (const char*)buf;
#pragma unroll
        for (int kt = 0; kt < 9; ++kt) {
            int ktg = ch * 9 + kt;
            half8 bf0 = *(const half8*)(WSP + (size_t)(((wc*2 + 0)*36 + ktg)*64 + lane) * 8);
            half8 bf1 = *(const half8*)(WSP + (size_t)(((wc*2 + 1)*36 + ktg)*64 + lane) * 8);
#pragma unroll
            for (int rt = 0; rt < 2; ++rt) {
                int row = wr*32 + rt*16 + la15;
                half8 a = *(const half8*)(p + ((row*576 + kt*64 + lhi*16) ^ ((row & 7) << 4)));
                acc2[rt][0] = __builtin_amdgcn_mfma_f32_16x16x32_f16(a, bf0, acc2[rt][0], 0, 0, 0);
                acc2[rt][1] = __builtin_amdgcn_mfma_f32_16x16x32_f16(a, bf1, acc2[rt][1], 0, 0, 0);
            }
        }
    };

    // -------- pipelined chunk loop: 8 fourier (160k) + 4 spline (288k) ------
    computeFour(0, feat0);
    __syncthreads();
    for (int ph = 0; ph < 12; ++ph) {
        _Float16* nb = ((ph + 1) & 1) ? feat1 : feat0;
        const _Float16* cb = (ph & 1) ? feat1 : feat0;
        int nx = ph + 1;
        if (nx < 8)        computeFour(nx, nb);
        else if (nx < 12)  computeSpl(nx - 8, nb);
        if (ph < 8) mfmaFour(ph, cb);
        else        mfmaSpl(ph - 8, cb);
        __syncthreads();
    }

    // -------- LayerNorm epilogue --------------------------------------------
    // C/D frag: col = la15 (+tile base), row_in_tile = lhi*4 + j.
#pragma unroll
    for (int rt = 0; rt < 2; ++rt) {
#pragma unroll
        for (int j = 0; j < 4; ++j) {
            float x0 = 0.5f * acc1[rt][0][j];
            float x1 = 0.5f * acc1[rt][1][j];
            float x2 = 0.5f * acc2[rt][0][j];
            float x3 = 0.5f * acc2[rt][1][j];
            float s  = x0 + x1 + x2 + x3;
            float qq = x0*x0 + x1*x1 + x2*x2 + x3*x3;
#pragma unroll
            for (int m = 1; m < 16; m <<= 1) {
                s  += __shfl_xor(s, m);
                qq += __shfl_xor(qq, m);
            }
            if (la15 == 0) {
                int r = wr*32 + rt*16 + lhi*4 + j;
                redS[r][wc] = s;
                redQ[r][wc] = qq;
            }
        }
    }
    __syncthreads();
    if (tid < 64) {
        float s = redS[tid][0] + redS[tid][1] + redS[tid][2] + redS[tid][3];
        float qq = redQ[tid][0] + redQ[tid][1] + redQ[tid][2] + redQ[tid][3];
        float mu = s * (1.0f / 256.0f);
        float var = qq * (1.0f / 256.0f) - mu * mu;
        muS[tid] = mu;
        rsS[tid] = rsqrtf(var + 1e-5f);
    }
    __syncthreads();
    {
        int c10 = wc*32 + la15, c11 = c10 + 16;
        int c20 = c10 + 128,    c21 = c11 + 128;
        float g10 = LNW[c10]*SCW[c10], h10 = LNB[c10]*SCW[c10];
        float g11 = LNW[c11]*SCW[c11], h11 = LNB[c11]*SCW[c11];
        float g20 = LNW[c20]*SCW[c20], h20 = LNB[c20]*SCW[c20];
        float g21 = LNW[c21]*SCW[c21], h21 = LNB[c21]*SCW[c21];
#pragma unroll
        for (int rt = 0; rt < 2; ++rt) {
#pragma unroll
            for (int j = 0; j < 4; ++j) {
                int r = wr*32 + rt*16 + lhi*4 + j;
                float mu = muS[r], rr = rsS[r];
                size_t base = (size_t)(row0 + r) * 256;
                OUT[base + c10] = (0.5f*acc1[rt][0][j] - mu)*rr*g10 + h10;
                OUT[base + c11] = (0.5f*acc1[rt][1][j] - mu)*rr*g11 + h11;
                OUT[base + c20] = (0.5f*acc2[rt][0][j] - mu)*rr*g20 + h20;
                OUT[base + c21] = (0.5f*acc2[rt][1][j] - mu)*rr*g21 + h21;
            }
        }
    }
}

extern "C" void kernel_launch(void* const* d_in, const int* in_sizes, int n_in,
                              void* d_out, int out_size, void* d_ws, size_t ws_size,
                              hipStream_t stream) {
    const float* TS     = (const float*)d_in[0];
    const float* FTHETA = (const float*)d_in[1];
    const float* BFOUR  = (const float*)d_in[2];
    const float* FW     = (const float*)d_in[3];
    const float* W1W    = (const float*)d_in[4];
    const float* W1B    = (const float*)d_in[5];
    const float* BW     = (const float*)d_in[6];
    const float* SW     = (const float*)d_in[7];
    const float* SCW    = (const float*)d_in[8];
    const float* LNW    = (const float*)d_in[9];
    const float* LNB    = (const float*)d_in[10];
    float* OUT = (float*)d_out;

    _Float16* WFP = (_Float16*)d_ws;        // 163840 f16
    _Float16* WSP = WFP + 163840;           // 147456 f16

    hipLaunchKernelGGL(prep_kernel, dim3(1216), dim3(256), 0, stream,
                       FW, BW, SW, WFP, WSP);
    hipLaunchKernelGGL(fused_kernel, dim3(256), dim3(512), 0, stream,
                       TS, FTHETA, BFOUR, W1W, W1B, LNW, LNB, SCW, WFP, WSP, OUT);
}